// Round 13
// baseline (383.657 us; speedup 1.0000x reference)
//
#include <hip/hip_runtime.h>
#include <hip/hip_bf16.h>

// SegmentConv2d: fake-quant-int8 (global for x, per-128-oc-chunk for w) + 3x3 pad1 conv + bias.
// int8 path: quantize to real int8, conv with mfma_i32_16x16x64_i8 (exact int accum),
// scale+bias epilogue.
//
// Shapes: x[8][256][128][128] f32, w[512][256][3][3] f32, bias[512], out[8][512][128][128] f32.
//
// ws layout:
//   [0..63]           : amax[5] (uint bits, written by k_amax2 - no atomics)
//   [64..79]          : 16B zeros (OOB redirect / zero B-fragments)
//   [256..13567]      : per-block amax partials float[3328] (x: 0..2047, w: 2048..3199)
//   [16384..)         : qx int8 NHWC  [n][h][w][c]  = 33,554,432 B
//   [16384+32M..)     : qw int8       [r*3+s][oc][c] = 1,179,648 B

typedef int i32x4 __attribute__((ext_vector_type(4)));

__device__ __forceinline__ void llds16(const void* g, void* l) {
    __builtin_amdgcn_global_load_lds(
        (const __attribute__((address_space(1))) void*)g,
        (__attribute__((address_space(3))) void*)l,
        16, 0, 0);
}

__device__ __forceinline__ float f4max(float4 v) {
    return fmaxf(fmaxf(fabsf(v.x), fabsf(v.y)), fmaxf(fabsf(v.z), fabsf(v.w)));
}

// ---------------- amax stage 1: per-block partial maxima (NO atomics) ----------------
__global__ __launch_bounds__(256) void k_amax(const float4* __restrict__ x,
                                              const float4* __restrict__ w4,
                                              float* __restrict__ part) {
    __shared__ float red[4];
    int t = threadIdx.x;
    float m = 0.f;
    if (blockIdx.x < 2048) {
        int tid = blockIdx.x * 256 + t;
        float4 v[16];
#pragma unroll
        for (int k = 0; k < 16; ++k)
            v[k] = x[(size_t)tid + (size_t)k * 524288];
#pragma unroll
        for (int k = 0; k < 16; ++k) m = fmaxf(m, f4max(v[k]));
    } else {
        int b = blockIdx.x - 2048;          // 0..1151
        int chunk = b / 288;
        int tid = (b - chunk * 288) * 256 + t;
        m = f4max(w4[(size_t)chunk * 73728 + tid]);
    }
    for (int off = 32; off > 0; off >>= 1) m = fmaxf(m, __shfl_xor(m, off, 64));
    if ((t & 63) == 0) red[t >> 6] = m;
    __syncthreads();
    if (t == 0)
        part[blockIdx.x] = fmaxf(fmaxf(red[0], red[1]), fmaxf(red[2], red[3]));
}

// ---------------- amax stage 2: reduce partials -> amaxb[0..4] ----------------
__global__ __launch_bounds__(256) void k_amax2(const float* __restrict__ part,
                                               unsigned* __restrict__ amaxb) {
    __shared__ float red[4];
    int t = threadIdx.x;
    float m = 0.f;
#pragma unroll
    for (int k = 0; k < 8; ++k) m = fmaxf(m, part[t + k * 256]);
    for (int off = 32; off > 0; off >>= 1) m = fmaxf(m, __shfl_xor(m, off, 64));
    if ((t & 63) == 0) red[t >> 6] = m;
    __syncthreads();
    if (t == 0)
        amaxb[0] = __float_as_uint(fmaxf(fmaxf(red[0], red[1]), fmaxf(red[2], red[3])));
    // w: one wave per chunk, 288 partials each
    int c = t >> 6, l = t & 63;
    float wm = 0.f;
#pragma unroll
    for (int k = 0; k < 5; ++k) {
        int i = l + k * 64;
        if (i < 288) wm = fmaxf(wm, part[2048 + c * 288 + i]);
    }
    for (int off = 32; off > 0; off >>= 1) wm = fmaxf(wm, __shfl_xor(wm, off, 64));
    if (l == 0) amaxb[1 + c] = __float_as_uint(wm);
}

// ---------------- quantize x : NCHW f32 -> NHWC int8 ----------------
__global__ __launch_bounds__(256) void k_quant_x(const float* __restrict__ x,
                                                 signed char* __restrict__ qx,
                                                 const unsigned* __restrict__ amaxb) {
    float inv = 127.0f / fmaxf(__uint_as_float(amaxb[0]), 1e-12f);
    int row = blockIdx.x;                 // n*128 + h
    int n = row >> 7, h = row & 127;
    int t = threadIdx.x;
    int w4 = t & 31, cg = t >> 5;         // w4: float4 slot along w; cg in [0,8)
    const float* base = x + (size_t)n * 256 * 16384 + (size_t)h * 128 + w4 * 4;
#pragma unroll
    for (int pp = 0; pp < 2; ++pp) {
        int c0 = pp * 128 + cg * 16;
        float4 v[16];
#pragma unroll
        for (int j = 0; j < 16; ++j)
            v[j] = *(const float4*)(base + (size_t)(c0 + j) * 16384);
#pragma unroll
        for (int i = 0; i < 4; ++i) {
            unsigned wds[4];
#pragma unroll
            for (int jg = 0; jg < 4; ++jg) {
                unsigned u = 0;
#pragma unroll
                for (int jj = 0; jj < 4; ++jj) {
                    float f = (&v[jg * 4 + jj].x)[i];
                    int q = (int)fminf(fmaxf(rintf(f * inv), -128.f), 127.f);
                    u |= ((unsigned)(q & 255)) << (8 * jj);
                }
                wds[jg] = u;
            }
            *(uint4*)&qx[(size_t)row * 32768 + (size_t)(w4 * 4 + i) * 256 + c0] =
                make_uint4(wds[0], wds[1], wds[2], wds[3]);
        }
    }
}

// ---------------- quantize w : OIHW f32 -> [rs][oc][c] int8 ----------------
__global__ void k_quant_w(const float* __restrict__ wsrc, signed char* __restrict__ qw,
                          const unsigned* __restrict__ amaxb) {
    int idx = blockIdx.x * 256 + threadIdx.x;   // 131072 = 512 blocks
    int oc = idx >> 8, c = idx & 255;
    float inv = 127.0f / fmaxf(__uint_as_float(amaxb[1 + (oc >> 7)]), 1e-12f);
    const float* src = wsrc + (size_t)idx * 9;
    float v[9];
#pragma unroll
    for (int rs = 0; rs < 9; ++rs) v[rs] = src[rs];
#pragma unroll
    for (int rs = 0; rs < 9; ++rs) {
        float qf = fminf(fmaxf(rintf(v[rs] * inv), -128.f), 127.f);
        qw[((size_t)(rs * 512 + oc)) * 256 + c] = (signed char)(int)qf;
    }
}

// ---------------- conv : implicit GEMM with mfma_i32_16x16x64_i8 ----------------
// Round-13: round-6 skeleton (best measured: grid 2048, 4 waves, 128oc x 256px tile,
// 2 blocks/CU, stageW + 2 barriers per (cb,r) phase) with ONE structural change:
// B (pixel) fragments come DIRECTLY FROM GLOBAL qx, not LDS.
//  * A wave's B-load is 16 px x 256B = sixteen fully-covered 64B lines (perfectly
//    coalesced); qx is L2-resident per XCD (4.2 MB/image, XCD owns one image).
//  * xs staging is deleted entirely (its global_load_lds bursts, halo zeroing,
//    LDS traffic, and barrier coupling). LDS holds only wt (real 4-wave reuse).
//  * Per-wave LDS reads: 36 -> 24 ds_read_b128 per phase (-33%, 3.6 -> 2.4 GB);
//    B moves to the underused vmem/L2 pipe (12us aggregate at L2 BW).
//  * B double-buffered in regs: b0/b1 issued one MFMA-cluster (~650cy) ahead;
//    b(s0),b(s1) issued BEFORE stageW so they land under the barrier's drain.
//    (Round-5's global-A failure was unprefetched latency chaining; this isn't.)
// Register budget at the (256,2) cap: acc 128 AGPR + a 32 + b0/b1 32 + addr ~50
// ~= 242/256 (xs addressing freed). Spill tell = WRITE_SIZE inflation.
__global__ __launch_bounds__(256, 2) void k_conv(
    const signed char* __restrict__ qx, const signed char* __restrict__ qw,
    const signed char* __restrict__ zb, const unsigned* __restrict__ amaxb,
    const float* __restrict__ bias, float* __restrict__ out) {
    __shared__ __align__(16) signed char wt[3 * 128 * 64];  // 24576 B
    int orig = blockIdx.x;                      // 0..2047, nwg % 8 == 0
    int wgid = (orig & 7) * 256 + (orig >> 3);  // bijective XCD swizzle
    int rowpair = wgid >> 2, ocg = wgid & 3;    // ocg: 128-oc group == weight chunk
    int n = rowpair >> 6;                       // 64 rowpairs per image
    int h0 = (rowpair & 63) * 2;
    int t = threadIdx.x, wid = t >> 6, lane = t & 63;
    int lp = lane & 15, hi = lane >> 4;
    int rowsel = wid >> 1, whalf = wid & 1;

    i32x4 acc[8][4] = {};

    auto stageW = [&](int cb, int r) {
        // wt: 3 s x 128 oc x 4 q4 = 1536 x 16B
#pragma unroll
        for (int i = 0; i < 6; ++i) {
            int idx = t + i * 256;       // 0..1535
            int s = idx >> 9, rem = idx & 511;
            int oc = rem >> 2, q4 = rem & 3;
            int q4s = q4 ^ ((oc >> 1) & 3);
            const signed char* src = qw
                + (size_t)((r * 3 + s) * 512 + ocg * 128 + oc) * 256 + cb * 64 + q4s * 16;
            llds16(src, wt + (size_t)(i * 256 + wid * 64) * 16);
        }
    };
    auto rdA = [&](int s, i32x4* a) {
#pragma unroll
        for (int mf = 0; mf < 8; ++mf) {
            int ocr = mf * 16 + lp;
            a[mf] = *(const i32x4*)&wt[s * 8192 + ocr * 64
                                       + ((hi ^ ((ocr >> 1) & 3)) << 4)];
        }
    };
    auto ldB = [&](int cb, int rowk, int s, i32x4* b) {
        int hh = h0 - 1 + rowk;
        bool rok = (hh >= 0) && (hh < 128);
        const signed char* rowbase =
            qx + (size_t)(n * 128 + (rok ? hh : 0)) * 32768 + cb * 64 + hi * 16;
#pragma unroll
        for (int nf = 0; nf < 4; ++nf) {
            int w = whalf * 64 + nf * 16 + lp + s - 1;   // [-1..128]
            bool ok = rok && (w >= 0) && (w < 128);
            const signed char* src = ok ? rowbase + (size_t)w * 256 : zb;
            b[nf] = *(const i32x4*)src;
        }
    };
    auto domm = [&](i32x4* a, i32x4* b) {
#pragma unroll
        for (int mf = 0; mf < 8; ++mf)
#pragma unroll
            for (int nf = 0; nf < 4; ++nf)
                acc[mf][nf] = __builtin_amdgcn_mfma_i32_16x16x64_i8(
                    a[mf], b[nf], acc[mf][nf], 0, 0, 0);
    };

    for (int cb = 0; cb < 4; ++cb) {
#pragma unroll
        for (int r = 0; r < 3; ++r) {
            int rowk = r + rowsel;
            i32x4 a[8], b0[4], b1[4];
            ldB(cb, rowk, 0, b0);          // issued pre-barrier: land under wt drain
            ldB(cb, rowk, 1, b1);
            stageW(cb, r);
            __syncthreads();               // wt landed (implicit vmcnt drain)
            rdA(0, a);
            domm(a, b0);                   // s=0
            ldB(cb, rowk, 2, b0);          // b(s2) in flight under s=1's MFMA
            rdA(1, a);
            domm(a, b1);                   // s=1
            rdA(2, a);
            domm(a, b0);                   // s=2
            __syncthreads();               // wt reads done -> reusable
        }
    }

    float sx = fmaxf(__uint_as_float(amaxb[0]), 1e-12f) / 127.0f;
    float sw = fmaxf(__uint_as_float(amaxb[1 + ocg]), 1e-12f) / 127.0f;
    float sc = sx * sw;
    int h = h0 + rowsel;
#pragma unroll
    for (int mf = 0; mf < 8; ++mf)
#pragma unroll
        for (int nf = 0; nf < 4; ++nf)
#pragma unroll
            for (int j = 0; j < 4; ++j) {
                int oc = ocg * 128 + mf * 16 + hi * 4 + j;
                int px = whalf * 64 + nf * 16 + lp;
                out[((size_t)(n * 512 + oc) * 128 + h) * 128 + px] =
                    (float)acc[mf][nf][j] * sc + bias[oc];
            }
}

extern "C" void kernel_launch(void* const* d_in, const int* in_sizes, int n_in,
                              void* d_out, int out_size, void* d_ws, size_t ws_size,
                              hipStream_t stream) {
    const float* x    = (const float*)d_in[0];
    const float* wgt  = (const float*)d_in[1];
    const float* bias = (const float*)d_in[2];
    float* out = (float*)d_out;

    unsigned* amaxb = (unsigned*)d_ws;
    float* part = (float*)((char*)d_ws + 256);
    signed char* qx = (signed char*)d_ws + 16384;
    signed char* qw = (signed char*)d_ws + 16384 + 33554432;
    const signed char* zb = (const signed char*)d_ws + 64;   // 16B zeros for OOB

    hipMemsetAsync(d_ws, 0, 256, stream);   // zb zeros (amax slots overwritten by k_amax2)

    k_amax<<<3200, 256, 0, stream>>>((const float4*)x, (const float4*)wgt, part);
    k_amax2<<<1, 256, 0, stream>>>(part, amaxb);
    k_quant_x<<<1024, 256, 0, stream>>>(x, qx, amaxb);
    k_quant_w<<<512, 256, 0, stream>>>(wgt, qw, amaxb);
    k_conv<<<dim3(2048), 256, 0, stream>>>(qx, qw, zb, amaxb, bias, out);
}

// Round 14
// 246.627 us; speedup vs baseline: 1.5556x; 1.5556x over previous
//
#include <hip/hip_runtime.h>
#include <hip/hip_bf16.h>

// SegmentConv2d: fake-quant-int8 (global for x, per-128-oc-chunk for w) + 3x3 pad1 conv + bias.
// int8 path: quantize to real int8, conv with mfma_i32_32x32x32_i8 (exact int accum),
// scale+bias epilogue.
//
// Shapes: x[8][256][128][128] f32, w[512][256][3][3] f32, bias[512], out[8][512][128][128] f32.
//
// ws layout:
//   [0..63]           : amax[5] (uint bits, written by k_amax2 - no atomics)
//   [64..79]          : 16B zeros (OOB redirect for global_load_lds)
//   [256..13567]      : per-block amax partials float[3328] (x: 0..2047, w: 2048..3199)
//   [16384..)         : qx int8 NHWC  [n][h][w][c]  = 33,554,432 B
//   [16384+32M..)     : qw int8       [r*3+s][oc][c] = 1,179,648 B

typedef int i32x4 __attribute__((ext_vector_type(4)));
typedef int i32x16 __attribute__((ext_vector_type(16)));

__device__ __forceinline__ void llds16(const void* g, void* l) {
    __builtin_amdgcn_global_load_lds(
        (const __attribute__((address_space(1))) void*)g,
        (__attribute__((address_space(3))) void*)l,
        16, 0, 0);
}

__device__ __forceinline__ float f4max(float4 v) {
    return fmaxf(fmaxf(fabsf(v.x), fabsf(v.y)), fmaxf(fabsf(v.z), fabsf(v.w)));
}

// ---------------- amax stage 1: per-block partial maxima (NO atomics) ----------------
__global__ __launch_bounds__(256) void k_amax(const float4* __restrict__ x,
                                              const float4* __restrict__ w4,
                                              float* __restrict__ part) {
    __shared__ float red[4];
    int t = threadIdx.x;
    float m = 0.f;
    if (blockIdx.x < 2048) {
        int tid = blockIdx.x * 256 + t;
        float4 v[16];
#pragma unroll
        for (int k = 0; k < 16; ++k)
            v[k] = x[(size_t)tid + (size_t)k * 524288];
#pragma unroll
        for (int k = 0; k < 16; ++k) m = fmaxf(m, f4max(v[k]));
    } else {
        int b = blockIdx.x - 2048;          // 0..1151
        int chunk = b / 288;
        int tid = (b - chunk * 288) * 256 + t;
        m = f4max(w4[(size_t)chunk * 73728 + tid]);
    }
    for (int off = 32; off > 0; off >>= 1) m = fmaxf(m, __shfl_xor(m, off, 64));
    if ((t & 63) == 0) red[t >> 6] = m;
    __syncthreads();
    if (t == 0)
        part[blockIdx.x] = fmaxf(fmaxf(red[0], red[1]), fmaxf(red[2], red[3]));
}

// ---------------- amax stage 2: reduce partials -> amaxb[0..4] ----------------
__global__ __launch_bounds__(256) void k_amax2(const float* __restrict__ part,
                                               unsigned* __restrict__ amaxb) {
    __shared__ float red[4];
    int t = threadIdx.x;
    float m = 0.f;
#pragma unroll
    for (int k = 0; k < 8; ++k) m = fmaxf(m, part[t + k * 256]);
    for (int off = 32; off > 0; off >>= 1) m = fmaxf(m, __shfl_xor(m, off, 64));
    if ((t & 63) == 0) red[t >> 6] = m;
    __syncthreads();
    if (t == 0)
        amaxb[0] = __float_as_uint(fmaxf(fmaxf(red[0], red[1]), fmaxf(red[2], red[3])));
    // w: one wave per chunk, 288 partials each
    int c = t >> 6, l = t & 63;
    float wm = 0.f;
#pragma unroll
    for (int k = 0; k < 5; ++k) {
        int i = l + k * 64;
        if (i < 288) wm = fmaxf(wm, part[2048 + c * 288 + i]);
    }
    for (int off = 32; off > 0; off >>= 1) wm = fmaxf(wm, __shfl_xor(wm, off, 64));
    if (l == 0) amaxb[1 + c] = __float_as_uint(wm);
}

// ---------------- quantize x : NCHW f32 -> NHWC int8 ----------------
__global__ __launch_bounds__(256) void k_quant_x(const float* __restrict__ x,
                                                 signed char* __restrict__ qx,
                                                 const unsigned* __restrict__ amaxb) {
    float inv = 127.0f / fmaxf(__uint_as_float(amaxb[0]), 1e-12f);
    int row = blockIdx.x;                 // n*128 + h
    int n = row >> 7, h = row & 127;
    int t = threadIdx.x;
    int w4 = t & 31, cg = t >> 5;         // w4: float4 slot along w; cg in [0,8)
    const float* base = x + (size_t)n * 256 * 16384 + (size_t)h * 128 + w4 * 4;
#pragma unroll
    for (int pp = 0; pp < 2; ++pp) {
        int c0 = pp * 128 + cg * 16;
        float4 v[16];
#pragma unroll
        for (int j = 0; j < 16; ++j)
            v[j] = *(const float4*)(base + (size_t)(c0 + j) * 16384);
#pragma unroll
        for (int i = 0; i < 4; ++i) {
            unsigned wds[4];
#pragma unroll
            for (int jg = 0; jg < 4; ++jg) {
                unsigned u = 0;
#pragma unroll
                for (int jj = 0; jj < 4; ++jj) {
                    float f = (&v[jg * 4 + jj].x)[i];
                    int q = (int)fminf(fmaxf(rintf(f * inv), -128.f), 127.f);
                    u |= ((unsigned)(q & 255)) << (8 * jj);
                }
                wds[jg] = u;
            }
            *(uint4*)&qx[(size_t)row * 32768 + (size_t)(w4 * 4 + i) * 256 + c0] =
                make_uint4(wds[0], wds[1], wds[2], wds[3]);
        }
    }
}

// ---------------- quantize w : OIHW f32 -> [rs][oc][c] int8 ----------------
__global__ void k_quant_w(const float* __restrict__ wsrc, signed char* __restrict__ qw,
                          const unsigned* __restrict__ amaxb) {
    int idx = blockIdx.x * 256 + threadIdx.x;   // 131072 = 512 blocks
    int oc = idx >> 8, c = idx & 255;
    float inv = 127.0f / fmaxf(__uint_as_float(amaxb[1 + (oc >> 7)]), 1e-12f);
    const float* src = wsrc + (size_t)idx * 9;
    float v[9];
#pragma unroll
    for (int rs = 0; rs < 9; ++rs) v[rs] = src[rs];
#pragma unroll
    for (int rs = 0; rs < 9; ++rs) {
        float qf = fminf(fmaxf(rintf(v[rs] * inv), -128.f), 127.f);
        qw[((size_t)(rs * 512 + oc)) * 256 + c] = (signed char)(int)qf;
    }
}

// ---------------- conv : implicit GEMM with mfma_i32_32x32x32_i8 ----------------
// Round-14: round-6 skeleton byte-for-byte (grid 2048 XCD-swizzled, 4 waves,
// 128oc x 256px tile, 57.8 KB LDS, (256,2) -> 2 blocks/CU, stageX/stageW + 2
// barriers per (cb,r) phase) with the MFMA shape swapped 16x16x64 -> 32x32x32 and
// a fragment-level software pipeline:
//  * Per (s,ks) step the operand set is a[4]+b[2] = 24 VGPR (vs 48 for 16x16x64),
//    so a named double-buffer costs 48 VGPR and FITS at the 2-block register cap
//    (acc 128 AGPR + 48 + addr ~= 215 < 256). r11's identical idea spilled at 96.
//  * reads(u+1) issued before mm(u) -> each wave demands LDS port and MFMA pipe
//    simultaneously; overlap no longer relies on convoy-free block drift.
//  * 48 MFMA/phase instead of 96 (same FLOPs; i8 32x32 ubench 4404 vs 3944 TOPS).
// Swizzle algebra unchanged: logical quad q = ks*2 + (lane>>5), physical quad =
// q ^ ((row_or_slot>>1)&3); staging (inverse-permuted global source) untouched.
// A layout: row = lane&31, k = (lane>>5)*16+e (mirrors the verified 16x16x64
// pattern). C/D: col = lane&31, row = (reg&3)+8*(reg>>2)+4*(lane>>5).
__global__ __launch_bounds__(256, 2) void k_conv(
    const signed char* __restrict__ qx, const signed char* __restrict__ qw,
    const signed char* __restrict__ zb, const unsigned* __restrict__ amaxb,
    const float* __restrict__ bias, float* __restrict__ out) {
    __shared__ __align__(16) signed char xs[4 * 8320];      // 33280 B
    __shared__ __align__(16) signed char wt[3 * 128 * 64];  // 24576 B
    int orig = blockIdx.x;                      // 0..2047, nwg % 8 == 0
    int wgid = (orig & 7) * 256 + (orig >> 3);  // bijective XCD swizzle
    int rowpair = wgid >> 2, ocg = wgid & 3;    // ocg: 128-oc group == weight chunk
    int n = rowpair >> 6;                       // 64 rowpairs per image
    int h0 = (rowpair & 63) * 2;
    int t = threadIdx.x, wid = t >> 6, lane = t & 63;
    int l31 = lane & 31, hi2 = lane >> 5;
    int rowsel = wid >> 1, whalf = wid & 1;

    i32x16 acc[4][2] = {};

    auto stageX = [&](int cb) {
        // xs: 4 rows x 130 slots x 4 q4 = 2080 x 16B, lane-linear LDS dest
#pragma unroll
        for (int i = 0; i < 9; ++i) {
            int idx = t + i * 256;
            if (idx < 2080) {
                int rowk = idx / 520;
                int j = idx - rowk * 520;
                int wr = j >> 2, q4 = j & 3;
                int wg = wr - 1;
                int hh = h0 - 1 + rowk;
                int q4s = q4 ^ ((wr >> 1) & 3);
                const signed char* src = (hh >= 0 && hh < 128 && wg >= 0 && wg < 128)
                    ? qx + (size_t)(n * 128 + hh) * 32768 + wg * 256 + cb * 64 + q4s * 16
                    : zb;
                llds16(src, xs + (size_t)(i * 256 + wid * 64) * 16);
            }
        }
    };
    auto stageW = [&](int cb, int r) {
        // wt: 3 s x 128 oc x 4 q4 = 1536 x 16B
#pragma unroll
        for (int i = 0; i < 6; ++i) {
            int idx = t + i * 256;       // 0..1535
            int s = idx >> 9, rem = idx & 511;
            int oc = rem >> 2, q4 = rem & 3;
            int q4s = q4 ^ ((oc >> 1) & 3);
            const signed char* src = qw
                + (size_t)((r * 3 + s) * 512 + ocg * 128 + oc) * 256 + cb * 64 + q4s * 16;
            llds16(src, wt + (size_t)(i * 256 + wid * 64) * 16);
        }
    };
    auto rdA = [&](int u, i32x4* a) {            // u = s*2 + ks
        int s = u >> 1, ks = u & 1;
        int q = ks * 2 + hi2;
#pragma unroll
        for (int mf = 0; mf < 4; ++mf) {
            int ocr = mf * 32 + l31;
            a[mf] = *(const i32x4*)&wt[s * 8192 + ocr * 64
                                       + ((q ^ ((ocr >> 1) & 3)) << 4)];
        }
    };
    auto rdB = [&](int u, int rowk, i32x4* b) {
        int s = u >> 1, ks = u & 1;
        int q = ks * 2 + hi2;
#pragma unroll
        for (int nf = 0; nf < 2; ++nf) {
            int slot = whalf * 64 + nf * 32 + l31 + s;
            b[nf] = *(const i32x4*)&xs[rowk * 8320 + slot * 64
                                       + ((q ^ ((slot >> 1) & 3)) << 4)];
        }
    };
    auto domm = [&](i32x4* a, i32x4* b) {
#pragma unroll
        for (int mf = 0; mf < 4; ++mf)
#pragma unroll
            for (int nf = 0; nf < 2; ++nf)
                acc[mf][nf] = __builtin_amdgcn_mfma_i32_32x32x32_i8(
                    a[mf], b[nf], acc[mf][nf], 0, 0, 0);
    };

    for (int cb = 0; cb < 4; ++cb) {
#pragma unroll
        for (int r = 0; r < 3; ++r) {
            if (r == 0) stageX(cb);
            stageW(cb, r);
            __syncthreads();               // staging landed (implicit vmcnt drain)
            int rowk = r + rowsel;
            // 6-step (s,ks) software pipeline: reads(u+1) in flight under mm(u)
            i32x4 aP[4], bP[2], aQ[4], bQ[2];
            rdA(0, aP); rdB(0, rowk, bP);
            rdA(1, aQ); rdB(1, rowk, bQ);
            domm(aP, bP);                  // u=0
            rdA(2, aP); rdB(2, rowk, bP);
            domm(aQ, bQ);                  // u=1
            rdA(3, aQ); rdB(3, rowk, bQ);
            domm(aP, bP);                  // u=2
            rdA(4, aP); rdB(4, rowk, bP);
            domm(aQ, bQ);                  // u=3
            rdA(5, aQ); rdB(5, rowk, bQ);
            domm(aP, bP);                  // u=4
            domm(aQ, bQ);                  // u=5
            __syncthreads();               // fragment reads done -> wt/xs reusable
        }
    }

    float sx = fmaxf(__uint_as_float(amaxb[0]), 1e-12f) / 127.0f;
    float sw = fmaxf(__uint_as_float(amaxb[1 + ocg]), 1e-12f) / 127.0f;
    float sc = sx * sw;
    int h = h0 + rowsel;
#pragma unroll
    for (int mf = 0; mf < 4; ++mf)
#pragma unroll
        for (int nf = 0; nf < 2; ++nf)
#pragma unroll
            for (int j = 0; j < 16; ++j) {
                int oc = ocg * 128 + mf * 32 + (j & 3) + 8 * (j >> 2) + 4 * hi2;
                int px = whalf * 64 + nf * 32 + l31;
                out[((size_t)(n * 512 + oc) * 128 + h) * 128 + px] =
                    (float)acc[mf][nf][j] * sc + bias[oc];
            }
}

extern "C" void kernel_launch(void* const* d_in, const int* in_sizes, int n_in,
                              void* d_out, int out_size, void* d_ws, size_t ws_size,
                              hipStream_t stream) {
    const float* x    = (const float*)d_in[0];
    const float* wgt  = (const float*)d_in[1];
    const float* bias = (const float*)d_in[2];
    float* out = (float*)d_out;

    unsigned* amaxb = (unsigned*)d_ws;
    float* part = (float*)((char*)d_ws + 256);
    signed char* qx = (signed char*)d_ws + 16384;
    signed char* qw = (signed char*)d_ws + 16384 + 33554432;
    const signed char* zb = (const signed char*)d_ws + 64;   // 16B zeros for OOB redirect

    hipMemsetAsync(d_ws, 0, 256, stream);   // zb zeros (amax slots overwritten by k_amax2)

    k_amax<<<3200, 256, 0, stream>>>((const float4*)x, (const float4*)wgt, part);
    k_amax2<<<1, 256, 0, stream>>>(part, amaxb);
    k_quant_x<<<1024, 256, 0, stream>>>(x, qx, amaxb);
    k_quant_w<<<512, 256, 0, stream>>>(wgt, qw, amaxb);
    k_conv<<<dim3(2048), 256, 0, stream>>>(qx, qw, zb, amaxb, bias, out);
}